// Round 9
// baseline (2906.508 us; speedup 1.0000x reference)
//
#include <hip/hip_runtime.h>

typedef unsigned short u16;
typedef unsigned int   u32;
typedef unsigned long long u64;
typedef short s16x8 __attribute__((ext_vector_type(8)));
typedef float f32x4 __attribute__((ext_vector_type(4)));
typedef u32   u32x2 __attribute__((ext_vector_type(2)));
typedef u32   u32x4 __attribute__((ext_vector_type(4)));
typedef _Float16 f16x2 __attribute__((ext_vector_type(2)));

#define S_LEN 2048
#define BATCH 64
#define H_DIM 300
#define HP    304   // padded N (output) dim
#define KP    320   // padded K (contraction) dim

// ws layout (bytes)
#define OFF_WPAD 0u         // 304*320*2 = 194,560
#define OFF_BIAS 196608u    // 304*4
#define OFF_FLAG 198656u    // 4
#define OFF_H    200704u    // 64*160*4 (f16-pair packed h, hq layout)
#define OFF_POOL 278528u    // 2048*304*4 = 2,490,368
#define OFF_WHH  2768896u   // 320*160*4 = 204,800 (f16-pair packed W_hh)
#define OFF_XP   3158016u   // CH*64*304*4 (f32)

__device__ __forceinline__ float bf2f(u16 u){
  union { u32 i; float f; } v; v.i = ((u32)u) << 16; return v.f;
}
__device__ __forceinline__ u16 f2bf(float f){
  u32 i = __float_as_uint(f);
  u32 r = (i + 0x7fffu + ((i >> 16) & 1u)) >> 16;
  return (u16)r;
}
__device__ __forceinline__ f16x2 asH2(u32 u){
  union { u32 u; f16x2 h; } v; v.u = u; return v.h;
}
__device__ __forceinline__ u16 f2h(float f){
  union { _Float16 h; u16 u; } v; v.h = (_Float16)f; return v.u;
}

// v_dot2_f32_f16: c += a.x*b.x + a.y*b.y (f16 inputs, f32 accumulate)
#if __has_builtin(__builtin_amdgcn_fdot2)
#define FD(WU, HU, C) __builtin_amdgcn_fdot2(asH2(WU), asH2(HU), (C), false)
#else
__device__ __forceinline__ float fd_fb(u32 wu, u32 hu, float c){
  const f16x2 w = asH2(wu), h = asH2(hu);
  c = fmaf((float)w.x, (float)h.x, c);
  c = fmaf((float)w.y, (float)h.y, c);
  return c;
}
#define FD(WU, HU, C) fd_fb((WU), (HU), (C))
#endif

// ---------------------------------------------------------------------------
// detect: f32 vs bf16 input storage (bf16 emb exponents < 135 always).
// ---------------------------------------------------------------------------
__global__ __launch_bounds__(256) void detect(const u16* __restrict__ emb_raw,
                                              int* __restrict__ flag){
  __shared__ int big;
  if (threadIdx.x == 0) big = 0;
  __syncthreads();
  int loc = 0;
  for (int i = threadIdx.x; i < 1024; i += 256){
    const u32 e = ((u32)emb_raw[i] >> 7) & 0xFFu;
    if (e >= 135u) loc = 1;
  }
  if (loc) atomicOr(&big, 1);
  __syncthreads();
  if (threadIdx.x == 0) *flag = big;   // 1 = f32 inputs, 0 = bf16 inputs
}

// ---------------------------------------------------------------------------
// prep: zero pooled / packed hstate; padded bf16 W_ih [304][320]; fused fp32
// bias; f16-pair packed W_hh [320 rows][160 pairs] (zero padded).
// ---------------------------------------------------------------------------
__global__ __launch_bounds__(256) void prep(
    const void* __restrict__ Wih_raw, const void* __restrict__ Whh_raw,
    const void* __restrict__ bih_raw, const void* __restrict__ bhh_raw,
    const int* __restrict__ flag,
    u16* __restrict__ Wpad, u32* __restrict__ Whh16,
    float* __restrict__ biasp, float* __restrict__ pooled,
    u32* __restrict__ hstate)
{
  const bool isf32 = (*flag != 0);
  const int idx = blockIdx.x * 256 + threadIdx.x;
  if (idx < S_LEN * HP) pooled[idx] = 0.f;
  if (idx < BATCH * 160) hstate[idx] = 0u;
  if (idx < 320 * 160){
    const int r = idx / 160, j = idx % 160;
    const int k = 2 * j;
    float w0 = 0.f, w1 = 0.f;
    if (r < H_DIM){
      if (k < H_DIM)
        w0 = isf32 ? ((const float*)Whh_raw)[r * H_DIM + k]
                   : bf2f(((const u16*)Whh_raw)[r * H_DIM + k]);
      if (k + 1 < H_DIM)
        w1 = isf32 ? ((const float*)Whh_raw)[r * H_DIM + k + 1]
                   : bf2f(((const u16*)Whh_raw)[r * H_DIM + k + 1]);
    }
    Whh16[idx] = (u32)f2h(w0) | ((u32)f2h(w1) << 16);
  }
  if (idx < HP * KP){
    const int n = idx / KP, k = idx % KP;
    u16 v = 0;
    if (n < H_DIM && k < H_DIM){
      v = isf32 ? f2bf(((const float*)Wih_raw)[n * H_DIM + k])
                : ((const u16*)Wih_raw)[n * H_DIM + k];
    }
    Wpad[idx] = v;
  }
  if (idx < HP){
    float bv = 0.f;
    if (idx < H_DIM){
      bv = isf32 ? (((const float*)bih_raw)[idx] + ((const float*)bhh_raw)[idx])
                 : (bf2f(((const u16*)bih_raw)[idx]) + bf2f(((const u16*)bhh_raw)[idx]));
    }
    biasp[idx] = bv;
  }
}

// ---------------------------------------------------------------------------
// xp_gemm: xp[mrel][n] = emb[x[s0*64+mrel]] . W_ih[n,:] + b_ih[n] + b_hh[n]
// One block = 64 m-rows, 4 waves, MFMA 16x16x32 bf16. xp stored f32.
// ---------------------------------------------------------------------------
__global__ __launch_bounds__(256) void xp_gemm(
    const int* __restrict__ x, const void* __restrict__ emb_raw,
    const int* __restrict__ flag,
    const u16* __restrict__ Wpad, const float* __restrict__ biasp,
    float* __restrict__ xp, int s0)
{
  __shared__ u16 A[64 * KP];                 // 40 KB
  const bool isf32 = (*flag != 0);
  const int tid = threadIdx.x;
  const int m0g = s0 * BATCH + blockIdx.x * 64;   // global m of row 0
  const int m0r = blockIdx.x * 64;                // chunk-relative

  for (int t = tid; t < 640; t += 256){
    const int row = t / 10, wd = t % 10;
    *(u32*)&A[row * KP + H_DIM + wd * 2] = 0u;
  }
  for (int t = tid; t < 64 * 75; t += 256){
    const int row = t / 75, off = t % 75;
    const int tok = x[m0g + row];
    u64 pk;
    if (isf32){
      const float4 v = *(const float4*)((const float*)emb_raw + (size_t)tok * H_DIM + off * 4);
      pk = (u64)f2bf(v.x) | ((u64)f2bf(v.y) << 16)
         | ((u64)f2bf(v.z) << 32) | ((u64)f2bf(v.w) << 48);
    } else {
      pk = *(const u64*)((const u16*)emb_raw + (size_t)tok * H_DIM + off * 4);
    }
    *(u64*)&A[row * KP + off * 4] = pk;
  }
  __syncthreads();

  const int wave = tid >> 6, lane = tid & 63;
  const int lm = lane & 15, lq = lane >> 4;

  f32x4 acc[19];
#pragma unroll
  for (int nt = 0; nt < 19; ++nt) acc[nt] = (f32x4){0.f, 0.f, 0.f, 0.f};

#pragma unroll
  for (int ks = 0; ks < 10; ++ks){
    const int k = ks * 32 + lq * 8;
    const s16x8 af = *(const s16x8*)&A[(wave * 16 + lm) * KP + k];
#pragma unroll
    for (int nt = 0; nt < 19; ++nt){
      const s16x8 bf = *(const s16x8*)&Wpad[(nt * 16 + lm) * KP + k];
      acc[nt] = __builtin_amdgcn_mfma_f32_16x16x32_bf16(af, bf, acc[nt], 0, 0, 0);
    }
  }
#pragma unroll
  for (int nt = 0; nt < 19; ++nt){
    const int n = nt * 16 + lm;
    const float bv = biasp[n];
#pragma unroll
    for (int rr = 0; rr < 4; ++rr){
      const int m = m0r + wave * 16 + lq * 4 + rr;
      xp[(size_t)m * HP + n] = acc[nt][rr] + bv;
    }
  }
}

// ---------------------------------------------------------------------------
// recur: one block per batch b. 512 threads = 8 waves. Wave c owns k-pair
// chunk [19c, 19c+19) (8*19 = 152 pairs = 304 cols). Lane l owns rows
// {4l..4l+3, 256+l}. The 95 packed-f16 weight dwords/thread live in
// AGPRs a0-a94, pinned by physical name via inline asm (R5-R8: the RA
// spills or remats any VGPR working set this size; AGPRs with explicit
// clobbers are outside its reach). Reads are v_accvgpr_read (2-cyc VALU),
// dot via v_dot2_f32_f16. h as f16 pairs in per-wave-aligned LDS segs.
// ---------------------------------------------------------------------------
#define AWR(A, V) asm volatile("v_accvgpr_write_b32 a" #A ", %0" :: "v"((u32)(V)) : "a" #A)
#define DOT(A, H, ACC) { u32 wv_; \
  asm volatile("v_accvgpr_read_b32 %0, a" #A : "=v"(wv_)); \
  ACC = FD(wv_, (H), ACC); }

__global__ __launch_bounds__(512) void recur(
    const float* __restrict__ xp, const u32* __restrict__ Whh16,
    u32* __restrict__ hstate, float* __restrict__ pooled,
    float* __restrict__ dout, int s0, int len)
{
  const int b   = blockIdx.x;
  const int tid = threadIdx.x;
  const int c   = tid >> 6;        // k-pair chunk 0..7
  const int l   = tid & 63;
  const int j0  = c * 19;          // first pair index
  const int r0  = l * 4;           // rows r0..r0+3
  const int r4  = 256 + l;         // 5th row (rows 300..319 zero pad)

  __shared__ float part[8 * 320];  // 10 KB
  __shared__ u32 hq[160];          // h f16 pairs, hq[w*20+p], p<19 (pads 0)

  // ---- stage weights into AGPRs a0..a94 (once per launch) ----
  {
    const u32* w0p = Whh16 + (size_t)(r0 + 0) * 160 + j0;
    AWR(0,w0p[0]);  AWR(1,w0p[1]);  AWR(2,w0p[2]);  AWR(3,w0p[3]);  AWR(4,w0p[4]);
    AWR(5,w0p[5]);  AWR(6,w0p[6]);  AWR(7,w0p[7]);  AWR(8,w0p[8]);  AWR(9,w0p[9]);
    AWR(10,w0p[10]);AWR(11,w0p[11]);AWR(12,w0p[12]);AWR(13,w0p[13]);AWR(14,w0p[14]);
    AWR(15,w0p[15]);AWR(16,w0p[16]);AWR(17,w0p[17]);AWR(18,w0p[18]);
    const u32* w1p = Whh16 + (size_t)(r0 + 1) * 160 + j0;
    AWR(19,w1p[0]); AWR(20,w1p[1]); AWR(21,w1p[2]); AWR(22,w1p[3]); AWR(23,w1p[4]);
    AWR(24,w1p[5]); AWR(25,w1p[6]); AWR(26,w1p[7]); AWR(27,w1p[8]); AWR(28,w1p[9]);
    AWR(29,w1p[10]);AWR(30,w1p[11]);AWR(31,w1p[12]);AWR(32,w1p[13]);AWR(33,w1p[14]);
    AWR(34,w1p[15]);AWR(35,w1p[16]);AWR(36,w1p[17]);AWR(37,w1p[18]);
    const u32* w2p = Whh16 + (size_t)(r0 + 2) * 160 + j0;
    AWR(38,w2p[0]); AWR(39,w2p[1]); AWR(40,w2p[2]); AWR(41,w2p[3]); AWR(42,w2p[4]);
    AWR(43,w2p[5]); AWR(44,w2p[6]); AWR(45,w2p[7]); AWR(46,w2p[8]); AWR(47,w2p[9]);
    AWR(48,w2p[10]);AWR(49,w2p[11]);AWR(50,w2p[12]);AWR(51,w2p[13]);AWR(52,w2p[14]);
    AWR(53,w2p[15]);AWR(54,w2p[16]);AWR(55,w2p[17]);AWR(56,w2p[18]);
    const u32* w3p = Whh16 + (size_t)(r0 + 3) * 160 + j0;
    AWR(57,w3p[0]); AWR(58,w3p[1]); AWR(59,w3p[2]); AWR(60,w3p[3]); AWR(61,w3p[4]);
    AWR(62,w3p[5]); AWR(63,w3p[6]); AWR(64,w3p[7]); AWR(65,w3p[8]); AWR(66,w3p[9]);
    AWR(67,w3p[10]);AWR(68,w3p[11]);AWR(69,w3p[12]);AWR(70,w3p[13]);AWR(71,w3p[14]);
    AWR(72,w3p[15]);AWR(73,w3p[16]);AWR(74,w3p[17]);AWR(75,w3p[18]);
    const u32* w4p = Whh16 + (size_t)r4 * 160 + j0;
    AWR(76,w4p[0]); AWR(77,w4p[1]); AWR(78,w4p[2]); AWR(79,w4p[3]); AWR(80,w4p[4]);
    AWR(81,w4p[5]); AWR(82,w4p[6]); AWR(83,w4p[7]); AWR(84,w4p[8]); AWR(85,w4p[9]);
    AWR(86,w4p[10]);AWR(87,w4p[11]);AWR(88,w4p[12]);AWR(89,w4p[13]);AWR(90,w4p[14]);
    AWR(91,w4p[15]);AWR(92,w4p[16]);AWR(93,w4p[17]);AWR(94,w4p[18]);
  }

  if (tid < 160) hq[tid] = hstate[b * 160 + tid];

  const float* xpb = xp + (size_t)b * HP;        // chunk row t -> t*64+b
  float xv = 0.f;
  if (tid < 304) xv = xpb[tid];
  __syncthreads();

  for (int t = 0; t < len; ++t){
    float xnext = 0.f;
    if (tid < 304){
      const int tn = (t + 1 < len) ? (t + 1) : t;
      xnext = xpb[(size_t)tn * (BATCH * HP) + tid];
    }
    // wave-uniform h pairs for this wave's 19-pair chunk (16B-aligned base)
    const u32* hqc = hq + 20 * c;
    const u32x4 ha = *(const u32x4*)(hqc + 0);
    const u32x4 hb = *(const u32x4*)(hqc + 4);
    const u32x4 hc2 = *(const u32x4*)(hqc + 8);
    const u32x4 hd = *(const u32x4*)(hqc + 12);
    const u32x2 he = *(const u32x2*)(hqc + 16);
    const u32   hf2 = hqc[18];

    float s0v = 0.f, s1v = 0.f, s2v = 0.f, s3v = 0.f, s4v = 0.f;
    DOT(0,ha.x,s0v)  DOT(1,ha.y,s0v)  DOT(2,ha.z,s0v)  DOT(3,ha.w,s0v)
    DOT(4,hb.x,s0v)  DOT(5,hb.y,s0v)  DOT(6,hb.z,s0v)  DOT(7,hb.w,s0v)
    DOT(8,hc2.x,s0v) DOT(9,hc2.y,s0v) DOT(10,hc2.z,s0v)DOT(11,hc2.w,s0v)
    DOT(12,hd.x,s0v) DOT(13,hd.y,s0v) DOT(14,hd.z,s0v) DOT(15,hd.w,s0v)
    DOT(16,he.x,s0v) DOT(17,he.y,s0v) DOT(18,hf2,s0v)
    DOT(19,ha.x,s1v) DOT(20,ha.y,s1v) DOT(21,ha.z,s1v) DOT(22,ha.w,s1v)
    DOT(23,hb.x,s1v) DOT(24,hb.y,s1v) DOT(25,hb.z,s1v) DOT(26,hb.w,s1v)
    DOT(27,hc2.x,s1v)DOT(28,hc2.y,s1v)DOT(29,hc2.z,s1v)DOT(30,hc2.w,s1v)
    DOT(31,hd.x,s1v) DOT(32,hd.y,s1v) DOT(33,hd.z,s1v) DOT(34,hd.w,s1v)
    DOT(35,he.x,s1v) DOT(36,he.y,s1v) DOT(37,hf2,s1v)
    DOT(38,ha.x,s2v) DOT(39,ha.y,s2v) DOT(40,ha.z,s2v) DOT(41,ha.w,s2v)
    DOT(42,hb.x,s2v) DOT(43,hb.y,s2v) DOT(44,hb.z,s2v) DOT(45,hb.w,s2v)
    DOT(46,hc2.x,s2v)DOT(47,hc2.y,s2v)DOT(48,hc2.z,s2v)DOT(49,hc2.w,s2v)
    DOT(50,hd.x,s2v) DOT(51,hd.y,s2v) DOT(52,hd.z,s2v) DOT(53,hd.w,s2v)
    DOT(54,he.x,s2v) DOT(55,he.y,s2v) DOT(56,hf2,s2v)
    DOT(57,ha.x,s3v) DOT(58,ha.y,s3v) DOT(59,ha.z,s3v) DOT(60,ha.w,s3v)
    DOT(61,hb.x,s3v) DOT(62,hb.y,s3v) DOT(63,hb.z,s3v) DOT(64,hb.w,s3v)
    DOT(65,hc2.x,s3v)DOT(66,hc2.y,s3v)DOT(67,hc2.z,s3v)DOT(68,hc2.w,s3v)
    DOT(69,hd.x,s3v) DOT(70,hd.y,s3v) DOT(71,hd.z,s3v) DOT(72,hd.w,s3v)
    DOT(73,he.x,s3v) DOT(74,he.y,s3v) DOT(75,hf2,s3v)
    DOT(76,ha.x,s4v) DOT(77,ha.y,s4v) DOT(78,ha.z,s4v) DOT(79,ha.w,s4v)
    DOT(80,hb.x,s4v) DOT(81,hb.y,s4v) DOT(82,hb.z,s4v) DOT(83,hb.w,s4v)
    DOT(84,hc2.x,s4v)DOT(85,hc2.y,s4v)DOT(86,hc2.z,s4v)DOT(87,hc2.w,s4v)
    DOT(88,hd.x,s4v) DOT(89,hd.y,s4v) DOT(90,hd.z,s4v) DOT(91,hd.w,s4v)
    DOT(92,he.x,s4v) DOT(93,he.y,s4v) DOT(94,hf2,s4v)

    *(f32x4*)&part[c * 320 + r0] = (f32x4){s0v, s1v, s2v, s3v};
    part[c * 320 + r4] = s4v;
    __syncthreads();

    if (tid < 304){
      float sum = xv;
#pragma unroll
      for (int cc = 0; cc < 8; ++cc) sum += part[cc * 320 + tid];
      const float h = fmaxf(sum, 0.f);
      const int s = s0 + t;
      if (tid < H_DIM){
        atomicMax((u32*)(pooled + (size_t)s * HP + tid), __float_as_uint(h));
        if (s == S_LEN - 1) dout[S_LEN * 2 + b * H_DIM + tid] = h;
      }
      const int j = tid >> 1;            // pair 0..151
      const int w2 = j / 19, p2 = j - w2 * 19;
      ((u16*)hq)[((w2 * 20 + p2) << 1) | (tid & 1)] = f2h(h);
      xv = xnext;
    }
    __syncthreads();
  }
  if (tid < 160) hstate[b * 160 + tid] = hq[tid];
}

// ---------------------------------------------------------------------------
// outproj: out[s][c] = sum_i pooled[s][i] * W_out[c][i] + b_out[c]  (f32 out)
// ---------------------------------------------------------------------------
__global__ __launch_bounds__(128) void outproj(
    const float* __restrict__ pooled, const void* __restrict__ Wout_raw,
    const void* __restrict__ bout_raw, const int* __restrict__ flag,
    float* __restrict__ dout)
{
  const bool isf32 = (*flag != 0);
  const int s = blockIdx.x * 128 + threadIdx.x;   // 0..2047
  float a0, a1;
  if (isf32){ a0 = ((const float*)bout_raw)[0]; a1 = ((const float*)bout_raw)[1]; }
  else      { a0 = bf2f(((const u16*)bout_raw)[0]); a1 = bf2f(((const u16*)bout_raw)[1]); }
  for (int i = 0; i < H_DIM; ++i){
    const float p = pooled[(size_t)s * HP + i];
    float w0, w1;
    if (isf32){ w0 = ((const float*)Wout_raw)[i]; w1 = ((const float*)Wout_raw)[H_DIM + i]; }
    else      { w0 = bf2f(((const u16*)Wout_raw)[i]); w1 = bf2f(((const u16*)Wout_raw)[H_DIM + i]); }
    a0 = fmaf(p, w0, a0);
    a1 = fmaf(p, w1, a1);
  }
  dout[s * 2 + 0] = a0;
  dout[s * 2 + 1] = a1;
}

// ---------------------------------------------------------------------------
extern "C" void kernel_launch(void* const* d_in, const int* in_sizes, int n_in,
                              void* d_out, int out_size, void* d_ws, size_t ws_size,
                              hipStream_t stream)
{
  const int* x  = (const int*)d_in[0];
  const void* emb  = d_in[1];
  const void* Wih  = d_in[2];
  const void* Whh  = d_in[3];
  const void* bih  = d_in[4];
  const void* bhh  = d_in[5];
  const void* Wout = d_in[6];
  const void* bout = d_in[7];
  float* out = (float*)d_out;

  char* ws = (char*)d_ws;
  u16*   Wpad   = (u16*)(ws + OFF_WPAD);
  float* biasp  = (float*)(ws + OFF_BIAS);
  int*   flag   = (int*)(ws + OFF_FLAG);
  u32*   hstate = (u32*)(ws + OFF_H);
  float* pooled = (float*)(ws + OFF_POOL);
  u32*   Whh16  = (u32*)(ws + OFF_WHH);
  float* xp     = (float*)(ws + OFF_XP);

  // choose chunk size (steps) so OFF_XP + CH*64*304*4 fits in ws_size
  const size_t per_step = (size_t)BATCH * HP * 4;   // 77,824 B
  int CH = 16;
  const int cands[8] = {2048, 1024, 512, 256, 128, 64, 32, 16};
  for (int i = 0; i < 8; ++i){
    if ((size_t)OFF_XP + (size_t)cands[i] * per_step <= ws_size){ CH = cands[i]; break; }
  }
  const int nchunks = S_LEN / CH;

  detect<<<1, 256, 0, stream>>>((const u16*)emb, flag);
  prep<<<2432, 256, 0, stream>>>(Wih, Whh, bih, bhh, flag, Wpad, Whh16,
                                 biasp, pooled, hstate);
  for (int k = 0; k < nchunks; ++k){
    const int s0 = k * CH;
    xp_gemm<<<CH, 256, 0, stream>>>(x, emb, flag, Wpad, biasp, xp, s0);
    recur<<<64, 512, 0, stream>>>(xp, Whh16, hstate, pooled, out, s0, CH);
  }
  outproj<<<16, 128, 0, stream>>>(pooled, Wout, bout, flag, out);
}